// Round 5
// baseline (176.182 us; speedup 1.0000x reference)
//
#include <hip/hip_runtime.h>
#include <hip/hip_bf16.h>

// B=256, T=256, DM=384, DK=DV=64.
// k0: W -> Wt bf16 [192 cols][384 k], chunked layout for LDS staging.
// k1: FUSED, one block/batch (1024 thr = 16 waves), 3 barriers total:
//   Stage: ENTIRE Wt (147KB) -> LDS via 144x1KB global_load_lds; barrier.
//   Phase 1 (QKV GEMM): barrier-free 12-chunk K-loop. Wave = 32 rows x 96 cols
//     (8 row-groups x 2 col-groups): A (x fp32) global->VGPR (coalesced,
//     software-pipelined), B from LDS (XOR-swizzled, conflict-free), 12 MFMA/chunk.
//   Phase 2: barrier; K/V^T/Q written into dead Wt LDS region; barrier.
//   Phase 3: S=QK^T triangular per wave; fused causal softmax (no max-subtract).
//   Phase 4: P via per-wave scratch (C->A layout), PV from LDS V^T; fp32 out.

typedef __attribute__((ext_vector_type(8))) short short8;
typedef __attribute__((ext_vector_type(4))) float floatx4;

__device__ inline unsigned short f2bf(float f) {
  union { float f; unsigned u; } v; v.f = f;
  unsigned r = v.u + 0x7FFFu + ((v.u >> 16) & 1u);  // RNE
  return (unsigned short)(r >> 16);
}
__device__ inline unsigned pk2bf(float lo, float hi) {
  __hip_bfloat162 h = __float22bfloat162_rn(make_float2(lo, hi));
  union { __hip_bfloat162 h; unsigned u; } c; c.h = h;
  return c.u;
}

__device__ inline void glds16(const void* g, void* l) {
  __builtin_amdgcn_global_load_lds(
      (const __attribute__((address_space(1))) void*)g,
      (__attribute__((address_space(3))) void*)l, 16, 0, 0);
}

// ---------------- kernel 0: weight transpose/convert ----------------
__global__ void wt_kernel(const float* __restrict__ wq, const float* __restrict__ wk,
                          const float* __restrict__ wv, unsigned short* __restrict__ wt) {
  int idx = blockIdx.x * 256 + threadIdx.x;      // OUTPUT [mat][n][k]
  if (idx >= 3 * 64 * 384) return;
  int mat = idx / (64 * 384);
  int rem = idx % (64 * 384);
  int n = rem / 384, k = rem % 384;
  const float* w = (mat == 0) ? wq : ((mat == 1) ? wk : wv);
  wt[idx] = f2bf(w[k * 64 + n]);
}

// ---------------- kernel 1: fused QKV + attention ----------------
__global__ __launch_bounds__(1024) void fused_kernel(
    const float* __restrict__ x, const unsigned short* __restrict__ wt,
    float* __restrict__ out) {
  __shared__ __align__(16) unsigned char lds[147456];
  unsigned short* wtl = (unsigned short*)lds;                    // [12][192 cols][32 k]
  unsigned short* sK  = (unsigned short*)lds;                    // [256][72]   36864 B
  unsigned short* sVT = (unsigned short*)(lds + 36864);          // [64][264]   33792 B
  unsigned short* sQ  = (unsigned short*)(lds + 70656);          // [256][72]   36864 B
  unsigned short* scrA = (unsigned short*)(lds + 107520);        // 16 x 2304 B

  int tid = threadIdx.x, lane = tid & 63, w = tid >> 6;
  int m = lane & 15, q = lane >> 4;
  int rg = w >> 1, cg = w & 1;                  // rows [32rg,32rg+32), cols [96cg,96cg+96)
  int b = blockIdx.x;
  const float* xb = x + (size_t)b * 256 * 384;

  // ---- stage ALL of Wt: 144 issues of 1KB (9 per wave), XOR-swizzled granules
#pragma unroll
  for (int t = 0; t < 9; ++t) {
    int i = w * 9 + t;
    int chunk = i / 12, sub = i % 12;
    int c = sub * 16 + (lane >> 2);             // col staged by this lane
    int g = (lane & 3) ^ (c & 3);               // granule fetched -> slot lane&3
    glds16(wt + (size_t)c * 384 + chunk * 32 + g * 8,
           (void*)(wtl + i * 512));
  }

  // ---- prefetch A chunk 0 (overlaps glds drain)
  const float* arow0 = xb + (size_t)(32 * rg + m) * 384 + q * 8;
  const float* arow1 = arow0 + 16 * 384;
  float4 c00 = *(const float4*)arow0, c01 = *(const float4*)(arow0 + 4);
  float4 c10 = *(const float4*)arow1, c11 = *(const float4*)(arow1 + 4);

  floatx4 z = {0.f, 0.f, 0.f, 0.f};
  floatx4 acc[2][6];
#pragma unroll
  for (int a = 0; a < 2; ++a)
#pragma unroll
    for (int n = 0; n < 6; ++n) acc[a][n] = z;

  __syncthreads();                               // (1) Wt staged

  // ---- phase 1: barrier-free K-loop, 12 chunks of 32
#pragma unroll 1
  for (int ks = 0; ks < 12; ++ks) {
    float4 n00, n01, n10, n11;
    if (ks < 11) {                               // software pipeline: next chunk
      n00 = *(const float4*)(arow0 + (ks + 1) * 32);
      n01 = *(const float4*)(arow0 + (ks + 1) * 32 + 4);
      n10 = *(const float4*)(arow1 + (ks + 1) * 32);
      n11 = *(const float4*)(arow1 + (ks + 1) * 32 + 4);
    }
    short8 af[2];
    {
      union { short8 s; unsigned u[4]; } t0, t1;
      t0.u[0] = pk2bf(c00.x, c00.y); t0.u[1] = pk2bf(c00.z, c00.w);
      t0.u[2] = pk2bf(c01.x, c01.y); t0.u[3] = pk2bf(c01.z, c01.w);
      t1.u[0] = pk2bf(c10.x, c10.y); t1.u[1] = pk2bf(c10.z, c10.w);
      t1.u[2] = pk2bf(c11.x, c11.y); t1.u[3] = pk2bf(c11.z, c11.w);
      af[0] = t0.s; af[1] = t1.s;
    }
    const unsigned short* wck = wtl + ks * 6144;
#pragma unroll
    for (int nt = 0; nt < 6; ++nt) {
      int c = cg * 96 + nt * 16 + m;
      short8 bf = *(const short8*)&wck[c * 32 + (q ^ (m & 3)) * 8];
      acc[0][nt] = __builtin_amdgcn_mfma_f32_16x16x32_bf16(af[0], bf, acc[0][nt], 0, 0, 0);
      acc[1][nt] = __builtin_amdgcn_mfma_f32_16x16x32_bf16(af[1], bf, acc[1][nt], 0, 0, 0);
    }
    c00 = n00; c01 = n01; c10 = n10; c11 = n11;
  }

  __syncthreads();                               // (2) all Wt reads done

  // ---- phase 2: epilogue. col cb = 96cg+16nt: <64 -> Q, <128 -> K, else V^T
#pragma unroll
  for (int mt = 0; mt < 2; ++mt) {
    int rowb = 32 * rg + mt * 16 + q * 4;        // C-layout rows rowb..rowb+3
#pragma unroll
    for (int nt = 0; nt < 6; ++nt) {
      int cb = cg * 96 + nt * 16;
      if (cb < 128) {
#pragma unroll
        for (int j = 0; j < 4; ++j) {
          unsigned short val = f2bf(acc[mt][nt][j]);
          if (cb < 64) sQ[(rowb + j) * 72 + cb + m]      = val;
          else         sK[(rowb + j) * 72 + cb - 64 + m] = val;
        }
      } else {
        ushort4 pv;
        pv.x = f2bf(acc[mt][nt][0]); pv.y = f2bf(acc[mt][nt][1]);
        pv.z = f2bf(acc[mt][nt][2]); pv.w = f2bf(acc[mt][nt][3]);
        *(ushort4*)&sVT[(cb - 128 + m) * 264 + rowb] = pv;
      }
    }
  }

  __syncthreads();                               // (3) K/V^T/Q visible

  // ---- phase 3: S = Q K^T (wave w owns q-rows [16w,16w+16); tiles nt <= w)
  short8 qf0 = *(const short8*)(sQ + (w * 16 + m) * 72 + q * 8);
  short8 qf1 = *(const short8*)(sQ + (w * 16 + m) * 72 + 32 + q * 8);
  floatx4 sacc[16];
#pragma unroll
  for (int nt = 0; nt < 16; ++nt) {
    if (nt > w) continue;                        // wave-uniform triangular skip
    short8 kb0 = *(const short8*)(sK + (nt * 16 + m) * 72 + q * 8);
    short8 kb1 = *(const short8*)(sK + (nt * 16 + m) * 72 + 32 + q * 8);
    floatx4 t = __builtin_amdgcn_mfma_f32_16x16x32_bf16(qf0, kb0, z, 0, 0, 0);
    sacc[nt] = __builtin_amdgcn_mfma_f32_16x16x32_bf16(qf1, kb1, t, 0, 0, 0);
  }

  // ---- fused causal mask + softmax (no max-subtract: logits bounded)
  const float CSC = 0.18033688011112042f;        // log2(e)/sqrt(64)
  float inv_[4];
  int rbase = w * 16 + q * 4;
#pragma unroll
  for (int j = 0; j < 4; ++j) {
    int rgl = rbase + j;
    float sum = 0.f;
#pragma unroll
    for (int nt = 0; nt < 16; ++nt) {
      if (nt > w) continue;
      int col = nt * 16 + m;
      float p = (col <= rgl) ? exp2f(sacc[nt][j] * CSC) : 0.f;
      sacc[nt][j] = p;
      sum += p;
    }
    sum += __shfl_xor(sum, 1);
    sum += __shfl_xor(sum, 2);
    sum += __shfl_xor(sum, 4);
    sum += __shfl_xor(sum, 8);
    inv_[j] = 1.f / sum;                         // diagonal term -> sum >= 1
  }

  // ---- phase 4: O = P V, 64-col chunks through per-wave scratch
  unsigned short* scr = scrA + w * 1152;         // [16][72] bf16
  floatx4 o[4];
#pragma unroll
  for (int vt = 0; vt < 4; ++vt) o[vt] = z;
#pragma unroll
  for (int c = 0; c < 4; ++c) {
    if (4 * c > w) continue;
#pragma unroll
    for (int t = 0; t < 4; ++t) {
      int nt = 4 * c + t;
#pragma unroll
      for (int j = 0; j < 4; ++j) {
        unsigned short pv = (nt <= w) ? f2bf(sacc[nt][j] * inv_[j]) : (unsigned short)0;
        scr[(q * 4 + j) * 72 + t * 16 + m] = pv;
      }
    }
    short8 pf0 = *(const short8*)(scr + m * 72 + q * 8);
    short8 pf1 = *(const short8*)(scr + m * 72 + 32 + q * 8);
#pragma unroll
    for (int vt = 0; vt < 4; ++vt) {
      short8 vb0 = *(const short8*)(sVT + (vt * 16 + m) * 264 + c * 64 + q * 8);
      short8 vb1 = *(const short8*)(sVT + (vt * 16 + m) * 264 + c * 64 + 32 + q * 8);
      o[vt] = __builtin_amdgcn_mfma_f32_16x16x32_bf16(pf0, vb0, o[vt], 0, 0, 0);
      o[vt] = __builtin_amdgcn_mfma_f32_16x16x32_bf16(pf1, vb1, o[vt], 0, 0, 0);
    }
  }

  // ---- store O
  float* op = out + ((size_t)b * 256 + w * 16) * 64;
#pragma unroll
  for (int vt = 0; vt < 4; ++vt)
#pragma unroll
    for (int j = 0; j < 4; ++j)
      op[(q * 4 + j) * 64 + vt * 16 + m] = o[vt][j];
}

extern "C" void kernel_launch(void* const* d_in, const int* in_sizes, int n_in,
                              void* d_out, int out_size, void* d_ws, size_t ws_size,
                              hipStream_t stream) {
  const float* x  = (const float*)d_in[0];
  const float* wq = (const float*)d_in[1];
  const float* wk = (const float*)d_in[2];
  const float* wv = (const float*)d_in[3];
  float* out = (float*)d_out;

  unsigned short* wt = (unsigned short*)d_ws;   // Wt bf16 [192][384] = 147456 B

  wt_kernel<<<288, 256, 0, stream>>>(wq, wk, wv, wt);
  fused_kernel<<<256, 1024, 0, stream>>>(x, wt, out);
}